// Round 14
// baseline (202.559 us; speedup 1.0000x reference)
//
#include <hip/hip_runtime.h>
#include <hip/hip_bf16.h>
#include <stdint.h>

#define F_IN 128
#define H 64
#define NH 4
#define KCH_H 16
#define KCH_O 32
#define LOG2E 1.44269504088896f

typedef __attribute__((ext_vector_type(8))) short bf16x8;
typedef __attribute__((ext_vector_type(4))) float floatx4;

static __device__ __forceinline__ unsigned short f2bf(float v) {
    __hip_bfloat16 b = __float2bfloat16(v);
    return *(unsigned short*)&b;
}
static __device__ __forceinline__ float bf2f(unsigned short u) {
    return __uint_as_float((unsigned int)u << 16);
}

// ---------------------------------------------------------------------------
// prep: blocks [0, N/8) = wh role (Wh->Bpk bf16, x_res, s1h/s2h);
//       blocks [N/8, N/8 + (N/16)*8) = pack role (adj -> fragment bitmask).
__global__ void prep_kernel(const int* __restrict__ adj,
                            unsigned char* __restrict__ adjp,
                            const float* __restrict__ x,
                            const float* __restrict__ w_heads,
                            const float* __restrict__ a_heads,
                            const float* __restrict__ lin_w,
                            const float* __restrict__ lin_b,
                            unsigned short* __restrict__ Bpk,
                            float* __restrict__ x_res,
                            float* __restrict__ s1h,
                            float* __restrict__ s2h, int N) {
    const int bid = blockIdx.x;
    const int tid = threadIdx.x;
    const int KT = N >> 5;
    const int WH_BLOCKS = N / 8;

    if (bid >= WH_BLOCKS) {
        int idx = bid - WH_BLOCKS;
        int it = idx >> 3, rem = idx & 7, half = rem >> 2, zz = rem & 3;
        int i0 = it * 16;
        int n = tid & 15, q = (tid >> 4) & 3, w = tid >> 6;
        const int* row = adj + (size_t)(i0 + n) * N;
        unsigned char* dst = adjp + (size_t)it * KT * 64;
        int ktbase = half * (KT / 2) + zz * 16 + w;
#pragma unroll
        for (int j = 0; j < 4; ++j) {
            int kt = ktbase + 4 * j;
            int c0 = kt * 32 + q * 8;
            int4 a = *(const int4*)(row + c0);
            int4 b = *(const int4*)(row + c0 + 4);
            unsigned byte =
                (unsigned)(a.x > 0) | ((unsigned)(a.y > 0) << 1) |
                ((unsigned)(a.z > 0) << 2) | ((unsigned)(a.w > 0) << 3) |
                ((unsigned)(b.x > 0) << 4) | ((unsigned)(b.y > 0) << 5) |
                ((unsigned)(b.z > 0) << 6) | ((unsigned)(b.w > 0) << 7);
            dst[kt * 64 + q * 16 + n] = (unsigned char)byte;
        }
        return;
    }

    // ---- wh role ----
    int h = tid >> 6, f = tid & 63;
    int i0 = bid * 8;
    __shared__ float xs[8][F_IN];
    __shared__ float lwT[F_IN][65];
    for (int e = tid; e < 8 * F_IN; e += 256)
        xs[e >> 7][e & 127] = x[(size_t)(i0 + (e >> 7)) * F_IN + (e & 127)];
    for (int e = tid; e < 64 * F_IN; e += 256) {
        int ff = e >> 7, k = e & 127;
        lwT[k][ff] = lin_w[e];
    }
    __syncthreads();
    float acc[8];
#pragma unroll
    for (int r = 0; r < 8; ++r) acc[r] = 0.f;
    float xr0 = 0.f, xr1 = 0.f;
    const float* w = w_heads + (size_t)h * F_IN * H + f;
#pragma unroll 4
    for (int k = 0; k < F_IN; ++k) {
        float wv = w[(size_t)k * H];
#pragma unroll
        for (int r = 0; r < 8; ++r) acc[r] += xs[r][k] * wv;
        float wx = lwT[k][f];
        xr0 += xs[h][k] * wx;
        xr1 += xs[h + 4][k] * wx;
    }
    {
        int kt = i0 >> 5, qq = (i0 >> 3) & 3;
        union { unsigned short s[8]; uint4 v; } t;
#pragma unroll
        for (int r = 0; r < 8; ++r) t.s[r] = f2bf(acc[r]);
        unsigned short* d = Bpk +
            (((size_t)(h * KT + kt) * 4 + (f >> 4)) * 64 + qq * 16 + (f & 15)) * 8;
        *(uint4*)d = t.v;
    }
    float b = lin_b[f];
    x_res[(size_t)(i0 + h) * H + f] = xr0 + b;
    x_res[(size_t)(i0 + h + 4) * H + f] = xr1 + b;
    float a1v = a_heads[(size_t)h * 2 * H + f];
    float a2v = a_heads[(size_t)h * 2 * H + H + f];
#pragma unroll
    for (int r = 0; r < 8; ++r) {
        float t1 = acc[r] * a1v;
        float t2 = acc[r] * a2v;
#pragma unroll
        for (int off = 32; off > 0; off >>= 1) {
            t1 += __shfl_xor(t1, off, 64);
            t2 += __shfl_xor(t2, off, 64);
        }
        if (f == 0) {
            s1h[(size_t)h * N + i0 + r] = t1 * LOG2E;
            s2h[(size_t)h * N + i0 + r] = t2 * LOG2E;
        }
    }
}

// ---------------------------------------------------------------------------
// pv5: BARRIER-FREE K-loop. The whole chunk's B (KTC*4KB <= 32KB) is staged
// into LDS up front (KTC independent uint4 loads/thread = bulk streaming),
// all adj bytes pre-loaded to regs, ONE __syncthreads total. Inner loop is
// pure ds_read -> exp -> MFMA with no drain points. Coalesced bf16 partial
// epilogue (r13).
template <int KTC, int MINW>
__global__ __launch_bounds__(256, MINW)
void pv5_kernel(const unsigned char* __restrict__ adjp,
                const unsigned short* __restrict__ Bpk,
                const float* __restrict__ s1a,
                const float* __restrict__ s2a,
                unsigned short* __restrict__ outp, float* __restrict__ lp,
                int out_stride, int N) {
    const int h = blockIdx.y, z = blockIdx.z;
    const int KT = N >> 5;
    const int kt0 = z * KTC;
    const int tid = threadIdx.x;
    const int wave = tid >> 6, lane = tid & 63;
    const int n = lane & 15, q = lane >> 4;
    const int i0w = (blockIdx.x * 4 + wave) * 16;

    __shared__ float s2s[KTC * 32];
    __shared__ unsigned short ldsB[KTC][2048];
    __shared__ float lds_l[64];

    // bulk stage: s2 chunk + ALL B tiles (independent loads, deep pipeline)
    const float4* s2src = (const float4*)(s2a + (size_t)h * N + kt0 * 32);
    for (int e = tid; e < KTC * 8; e += 256) ((float4*)s2s)[e] = s2src[e];
    const unsigned short* Bb = Bpk + ((size_t)h * KT + kt0) * 2048 + tid * 8;
#pragma unroll
    for (int t = 0; t < KTC; ++t)
        *(uint4*)&ldsB[t][tid * 8] = *(const uint4*)(Bb + (size_t)t * 2048);

    const unsigned char* ap = adjp + ((size_t)(i0w >> 4) * KT + kt0) * 64 + lane;
    unsigned int a_all[KTC];
#pragma unroll
    for (int t = 0; t < KTC; ++t) a_all[t] = ap[(size_t)t * 64];
    const float s1v = s1a[(size_t)h * N + i0w + n];

    floatx4 acc[4];
    floatx4 accl = {0.f, 0.f, 0.f, 0.f};
#pragma unroll
    for (int g = 0; g < 4; ++g) acc[g] = (floatx4){0.f, 0.f, 0.f, 0.f};

    bf16x8 ones;
    {
        short one = (n == 0) ? (short)0x3F80 : (short)0;
#pragma unroll
        for (int jj = 0; jj < 8; ++jj) ones[jj] = one;
    }

    __syncthreads();   // the ONLY barrier before the epilogue

#pragma unroll
    for (int k = 0; k < KTC; ++k) {
        float4 sa = *(const float4*)&s2s[k * 32 + q * 8];
        float4 sb = *(const float4*)&s2s[k * 32 + q * 8 + 4];
        const float* sv = (const float*)&sa;
        const float* sw = (const float*)&sb;
        float e[8];
#pragma unroll
        for (int jj = 0; jj < 8; ++jj) {
            float sj = (jj < 4 ? sv[jj] : sw[jj - 4]);
            float tt = s1v + sj;
            float lr = fmaxf(tt, 0.2f * tt);
            lr = (a_all[k] & (1u << jj)) ? lr : -150.f;
            e[jj] = __builtin_amdgcn_exp2f(lr);
        }
        union { unsigned int u[4]; bf16x8 v; } u;
        u.u[0] = __builtin_amdgcn_perm(__float_as_uint(e[1]), __float_as_uint(e[0]), 0x07060302u);
        u.u[1] = __builtin_amdgcn_perm(__float_as_uint(e[3]), __float_as_uint(e[2]), 0x07060302u);
        u.u[2] = __builtin_amdgcn_perm(__float_as_uint(e[5]), __float_as_uint(e[4]), 0x07060302u);
        u.u[3] = __builtin_amdgcn_perm(__float_as_uint(e[7]), __float_as_uint(e[6]), 0x07060302u);

        bf16x8 bf0 = *(const bf16x8*)&ldsB[k][0 * 512 + lane * 8];
        bf16x8 bf1 = *(const bf16x8*)&ldsB[k][1 * 512 + lane * 8];
        bf16x8 bf2 = *(const bf16x8*)&ldsB[k][2 * 512 + lane * 8];
        bf16x8 bf3 = *(const bf16x8*)&ldsB[k][3 * 512 + lane * 8];

        acc[0] = __builtin_amdgcn_mfma_f32_16x16x32_bf16(u.v, bf0, acc[0], 0, 0, 0);
        acc[1] = __builtin_amdgcn_mfma_f32_16x16x32_bf16(u.v, bf1, acc[1], 0, 0, 0);
        acc[2] = __builtin_amdgcn_mfma_f32_16x16x32_bf16(u.v, bf2, acc[2], 0, 0, 0);
        acc[3] = __builtin_amdgcn_mfma_f32_16x16x32_bf16(u.v, bf3, acc[3], 0, 0, 0);
        accl   = __builtin_amdgcn_mfma_f32_16x16x32_bf16(u.v, ones, accl, 0, 0, 0);
    }

    // ---- epilogue: LDS-bounce then coalesced 16B stores ----
    __syncthreads();   // all waves done with ldsB
    unsigned short* lw = ((unsigned short*)ldsB) + wave * 1024;
#pragma unroll
    for (int r = 0; r < 4; ++r) {
        int row = q * 4 + r;
#pragma unroll
        for (int g = 0; g < 4; ++g)
            lw[row * 64 + g * 16 + n] = f2bf(acc[g][r]);
    }
    if (n == 0) {
#pragma unroll
        for (int r = 0; r < 4; ++r) lds_l[wave * 16 + q * 4 + r] = accl[r];
    }
    __syncthreads();
    unsigned short* obase = outp + ((size_t)z * N + i0w) * out_stride + h * 64;
#pragma unroll
    for (int j = 0; j < 2; ++j) {
        int c = j * 64 + lane;
        int row = c >> 3, ci = c & 7;
        *(uint4*)(obase + (size_t)row * out_stride + ci * 8) =
            *(const uint4*)(lw + row * 64 + ci * 8);
    }
    if (tid < 64) {
        float* lrow = lp + ((size_t)z * gridDim.y + h) * N + blockIdx.x * 64;
        lrow[tid] = lds_l[tid];
    }
}

// whout2: sum bf16 partials (vectorized), normalize, ELU, GEMM K=256;
// packed-B + folded scores.
__global__ void whout2_kernel(const unsigned short* __restrict__ hcp,
                              const float* __restrict__ lhp,
                              const float* __restrict__ w_out,
                              const float* __restrict__ a_out,
                              unsigned short* __restrict__ BpkO,
                              float* __restrict__ s1o,
                              float* __restrict__ s2o, int N) {
    int tid = threadIdx.x;
    int i0 = blockIdx.x * 8;
    int KT = N >> 5;
    __shared__ float hs[8][256];
    __shared__ float linv[8][NH];
    if (tid < 8 * NH) {
        int r = tid >> 2, hd = tid & 3;
        float l = 0.f;
#pragma unroll
        for (int p = 0; p < KCH_H; ++p)
            l += lhp[((size_t)p * NH + hd) * N + i0 + r];
        linv[r][hd] = 1.f / fmaxf(l, 1e-30f);
    }
    __syncthreads();
    const size_t ps = (size_t)N * 256;
    for (int e4 = tid; e4 < 8 * 64; e4 += 256) {
        int r = e4 >> 6, k4 = (e4 & 63) * 4;
        size_t off = (size_t)(i0 + r) * 256 + k4;
        float v0 = 0.f, v1 = 0.f, v2 = 0.f, v3 = 0.f;
#pragma unroll
        for (int p = 0; p < KCH_H; ++p) {
            ushort4 u = *(const ushort4*)(hcp + p * ps + off);
            v0 += bf2f(u.x); v1 += bf2f(u.y); v2 += bf2f(u.z); v3 += bf2f(u.w);
        }
        float li = linv[r][k4 >> 6];
        v0 *= li; v1 *= li; v2 *= li; v3 *= li;
        hs[r][k4]     = v0 > 0.f ? v0 : expm1f(v0);
        hs[r][k4 + 1] = v1 > 0.f ? v1 : expm1f(v1);
        hs[r][k4 + 2] = v2 > 0.f ? v2 : expm1f(v2);
        hs[r][k4 + 3] = v3 > 0.f ? v3 : expm1f(v3);
    }
    __syncthreads();
    int f = tid & 63, rl = tid >> 6;
    float a0 = 0.f, a1 = 0.f;
#pragma unroll 4
    for (int k = 0; k < 256; ++k) {
        float wv = w_out[(size_t)k * H + f];
        a0 += hs[rl][k] * wv;
        a1 += hs[rl + 4][k] * wv;
    }
    float w1 = a_out[f], w2 = a_out[H + f];
    float t10 = a0 * w1, t20 = a0 * w2, t11 = a1 * w1, t21 = a1 * w2;
#pragma unroll
    for (int off = 32; off > 0; off >>= 1) {
        t10 += __shfl_xor(t10, off, 64);
        t20 += __shfl_xor(t20, off, 64);
        t11 += __shfl_xor(t11, off, 64);
        t21 += __shfl_xor(t21, off, 64);
    }
    if (f == 0) {
        s1o[i0 + rl] = t10 * LOG2E;
        s2o[i0 + rl] = t20 * LOG2E;
        s1o[i0 + rl + 4] = t11 * LOG2E;
        s2o[i0 + rl + 4] = t21 * LOG2E;
    }
    __syncthreads();
    float* wsW = &hs[0][0];
    wsW[rl * 64 + f] = a0;
    wsW[(rl + 4) * 64 + f] = a1;
    __syncthreads();
    if (tid < 64) {
        int kt = i0 >> 5, qq = (i0 >> 3) & 3;
        int g = tid >> 4, nn = tid & 15;
        union { unsigned short s[8]; uint4 v; } t;
#pragma unroll
        for (int r = 0; r < 8; ++r) t.s[r] = f2bf(wsW[r * 64 + g * 16 + nn]);
        unsigned short* d = BpkO +
            (((size_t)kt * 4 + g) * 64 + qq * 16 + nn) * 8;
        *(uint4*)d = t.v;
    }
}

// final2: sum bf16 partials (vectorized), normalize, ELU, + x_res, GEMM, ELU.
__global__ void final2_kernel(const unsigned short* __restrict__ o2p,
                              const float* __restrict__ lop,
                              const float* __restrict__ x_res,
                              const float* __restrict__ outlin_w,
                              const float* __restrict__ outlin_b,
                              float* __restrict__ out, int N) {
    int tid = threadIdx.x;
    int f = tid & 63, rl = tid >> 6;
    int i0 = blockIdx.x * 8;
    __shared__ float hs[8][H];
    __shared__ float linv[8];
    if (tid < 8) {
        float l = 0.f;
#pragma unroll
        for (int p = 0; p < KCH_O; ++p) l += lop[(size_t)p * N + i0 + tid];
        linv[tid] = 1.f / fmaxf(l, 1e-30f);
    }
    __syncthreads();
    const size_t ps = (size_t)N * 64;
    if (tid < 8 * 16) {
        int r = tid >> 4, f4 = (tid & 15) * 4;
        size_t off = (size_t)(i0 + r) * 64 + f4;
        float v0 = 0.f, v1 = 0.f, v2 = 0.f, v3 = 0.f;
#pragma unroll
        for (int p = 0; p < KCH_O; ++p) {
            ushort4 u = *(const ushort4*)(o2p + p * ps + off);
            v0 += bf2f(u.x); v1 += bf2f(u.y); v2 += bf2f(u.z); v3 += bf2f(u.w);
        }
        float li = linv[r];
        v0 *= li; v1 *= li; v2 *= li; v3 *= li;
        v0 = v0 > 0.f ? v0 : expm1f(v0);
        v1 = v1 > 0.f ? v1 : expm1f(v1);
        v2 = v2 > 0.f ? v2 : expm1f(v2);
        v3 = v3 > 0.f ? v3 : expm1f(v3);
        const float* xr = x_res + off;
        hs[r][f4]     = v0 + xr[0];
        hs[r][f4 + 1] = v1 + xr[1];
        hs[r][f4 + 2] = v2 + xr[2];
        hs[r][f4 + 3] = v3 + xr[3];
    }
    __syncthreads();
    float b = outlin_b[f];
    float a0 = b, a1 = b;
#pragma unroll 8
    for (int k = 0; k < H; ++k) {
        float wv = outlin_w[(size_t)f * H + k];
        a0 += hs[rl][k] * wv;
        a1 += hs[rl + 4][k] * wv;
    }
    a0 = a0 > 0.f ? a0 : expm1f(a0);
    a1 = a1 > 0.f ? a1 : expm1f(a1);
    out[(size_t)(i0 + rl) * H + f] = a0;
    out[(size_t)(i0 + rl + 4) * H + f] = a1;
}

extern "C" void kernel_launch(void* const* d_in, const int* in_sizes, int n_in,
                              void* d_out, int out_size, void* d_ws, size_t ws_size,
                              hipStream_t stream) {
    const float* x        = (const float*)d_in[0];
    const int*   adj      = (const int*)d_in[1];
    const float* w_heads  = (const float*)d_in[2];
    const float* a_heads  = (const float*)d_in[3];
    const float* w_out    = (const float*)d_in[4];
    const float* a_out    = (const float*)d_in[5];
    const float* lin_w    = (const float*)d_in[6];
    const float* lin_b    = (const float*)d_in[7];
    const float* outlin_w = (const float*)d_in[8];
    const float* outlin_b = (const float*)d_in[9];
    float* out = (float*)d_out;

    const int N = in_sizes[0] / F_IN;  // 4096
    const int KT = N >> 5;             // 128

    char* p = (char*)d_ws;
    unsigned short* part = (unsigned short*)p;  p += (size_t)KCH_H * N * 256 * 2;  // 32 MB
    float* x_res  = (float*)p;  p += (size_t)N * 64 * 4;
    float* s1h    = (float*)p;  p += (size_t)NH * N * 4;
    float* s2h    = (float*)p;  p += (size_t)NH * N * 4;
    float* s1o    = (float*)p;  p += (size_t)N * 4;
    float* s2o    = (float*)p;  p += (size_t)N * 4;
    float* lh_part = (float*)p; p += (size_t)KCH_H * NH * N * 4;
    float* lo_part = (float*)p; p += (size_t)KCH_O * N * 4;
    unsigned short* Bpk  = (unsigned short*)p;  p += (size_t)NH * KT * 2048 * 2;
    unsigned short* BpkO = (unsigned short*)p;  p += (size_t)KT * 2048 * 2;
    unsigned char* adjp  = (unsigned char*)p;   p += (size_t)(N / 16) * KT * 64;

    prep_kernel<<<N / 8 + (N / 16) * 8, 256, 0, stream>>>(
        adj, adjp, x, w_heads, a_heads, lin_w, lin_b, Bpk, x_res, s1h, s2h, N);
    pv5_kernel<8, 4><<<dim3(N / 64, NH, KCH_H), 256, 0, stream>>>(
        adjp, Bpk, s1h, s2h, part, lh_part, NH * H, N);
    whout2_kernel<<<N / 8, 256, 0, stream>>>(part, lh_part, w_out, a_out,
                                             BpkO, s1o, s2o, N);
    pv5_kernel<4, 8><<<dim3(N / 64, 1, KCH_O), 256, 0, stream>>>(
        adjp, BpkO, s1o, s2o, part, lo_part, H, N);
    final2_kernel<<<N / 8, 256, 0, stream>>>(part, lo_part, x_res, outlin_w, outlin_b, out, N);
}

// Round 15
// 198.000 us; speedup vs baseline: 1.0230x; 1.0230x over previous
//
#include <hip/hip_runtime.h>
#include <hip/hip_bf16.h>
#include <stdint.h>

#define F_IN 128
#define H 64
#define NH 4
#define KCH_H 16
#define KCH_O 32
#define LOG2E 1.44269504088896f

typedef __attribute__((ext_vector_type(8))) short bf16x8;
typedef __attribute__((ext_vector_type(4))) float floatx4;

static __device__ __forceinline__ unsigned short f2bf(float v) {
    __hip_bfloat16 b = __float2bfloat16(v);
    return *(unsigned short*)&b;
}
static __device__ __forceinline__ float bf2f(unsigned short u) {
    return __uint_as_float((unsigned int)u << 16);
}

// ---------------------------------------------------------------------------
// prep: blocks [0, N/8) = wh role (Wh->Bpk bf16, x_res, E/F score factors);
//       blocks [N/8, ...) = pack role (adj -> fragment bitmask).
// E = exp2(s*log2e), F = exp2(0.2*s*log2e) so in-loop softmax needs NO exp:
// exp(lrelu(s1+s2)) = max(E1*E2, F1*F2)  (exp2 monotone).
__global__ void prep_kernel(const int* __restrict__ adj,
                            unsigned char* __restrict__ adjp,
                            const float* __restrict__ x,
                            const float* __restrict__ w_heads,
                            const float* __restrict__ a_heads,
                            const float* __restrict__ lin_w,
                            const float* __restrict__ lin_b,
                            unsigned short* __restrict__ Bpk,
                            float* __restrict__ x_res,
                            float* __restrict__ E1h, float* __restrict__ F1h,
                            float* __restrict__ E2h, float* __restrict__ F2h,
                            int N) {
    const int bid = blockIdx.x;
    const int tid = threadIdx.x;
    const int KT = N >> 5;
    const int WH_BLOCKS = N / 8;

    if (bid >= WH_BLOCKS) {
        int idx = bid - WH_BLOCKS;
        int it = idx >> 3, rem = idx & 7, half = rem >> 2, zz = rem & 3;
        int i0 = it * 16;
        int n = tid & 15, q = (tid >> 4) & 3, w = tid >> 6;
        const int* row = adj + (size_t)(i0 + n) * N;
        unsigned char* dst = adjp + (size_t)it * KT * 64;
        int ktbase = half * (KT / 2) + zz * 16 + w;
#pragma unroll
        for (int j = 0; j < 4; ++j) {
            int kt = ktbase + 4 * j;
            int c0 = kt * 32 + q * 8;
            int4 a = *(const int4*)(row + c0);
            int4 b = *(const int4*)(row + c0 + 4);
            unsigned byte =
                (unsigned)(a.x > 0) | ((unsigned)(a.y > 0) << 1) |
                ((unsigned)(a.z > 0) << 2) | ((unsigned)(a.w > 0) << 3) |
                ((unsigned)(b.x > 0) << 4) | ((unsigned)(b.y > 0) << 5) |
                ((unsigned)(b.z > 0) << 6) | ((unsigned)(b.w > 0) << 7);
            dst[kt * 64 + q * 16 + n] = (unsigned char)byte;
        }
        return;
    }

    // ---- wh role ----
    int h = tid >> 6, f = tid & 63;
    int i0 = bid * 8;
    __shared__ float xs[8][F_IN];
    __shared__ float lwT[F_IN][65];
    for (int e = tid; e < 8 * F_IN; e += 256)
        xs[e >> 7][e & 127] = x[(size_t)(i0 + (e >> 7)) * F_IN + (e & 127)];
    for (int e = tid; e < 64 * F_IN; e += 256) {
        int ff = e >> 7, k = e & 127;
        lwT[k][ff] = lin_w[e];
    }
    __syncthreads();
    float acc[8];
#pragma unroll
    for (int r = 0; r < 8; ++r) acc[r] = 0.f;
    float xr0 = 0.f, xr1 = 0.f;
    const float* w = w_heads + (size_t)h * F_IN * H + f;
#pragma unroll 4
    for (int k = 0; k < F_IN; ++k) {
        float wv = w[(size_t)k * H];
#pragma unroll
        for (int r = 0; r < 8; ++r) acc[r] += xs[r][k] * wv;
        float wx = lwT[k][f];
        xr0 += xs[h][k] * wx;
        xr1 += xs[h + 4][k] * wx;
    }
    {
        int kt = i0 >> 5, qq = (i0 >> 3) & 3;
        union { unsigned short s[8]; uint4 v; } t;
#pragma unroll
        for (int r = 0; r < 8; ++r) t.s[r] = f2bf(acc[r]);
        unsigned short* d = Bpk +
            (((size_t)(h * KT + kt) * 4 + (f >> 4)) * 64 + qq * 16 + (f & 15)) * 8;
        *(uint4*)d = t.v;
    }
    float b = lin_b[f];
    x_res[(size_t)(i0 + h) * H + f] = xr0 + b;
    x_res[(size_t)(i0 + h + 4) * H + f] = xr1 + b;
    float a1v = a_heads[(size_t)h * 2 * H + f];
    float a2v = a_heads[(size_t)h * 2 * H + H + f];
#pragma unroll
    for (int r = 0; r < 8; ++r) {
        float t1 = acc[r] * a1v;
        float t2 = acc[r] * a2v;
#pragma unroll
        for (int off = 32; off > 0; off >>= 1) {
            t1 += __shfl_xor(t1, off, 64);
            t2 += __shfl_xor(t2, off, 64);
        }
        if (f == 0) {
            float s1 = t1 * LOG2E, s2 = t2 * LOG2E;
            size_t o = (size_t)h * N + i0 + r;
            E1h[o] = __builtin_amdgcn_exp2f(s1);
            F1h[o] = __builtin_amdgcn_exp2f(0.2f * s1);
            E2h[o] = __builtin_amdgcn_exp2f(s2);
            F2h[o] = __builtin_amdgcn_exp2f(0.2f * s2);
        }
    }
}

// ---------------------------------------------------------------------------
// pv2: r13 structure (depth-2 pipelined LDS double-buffer, coalesced bf16
// epilogue) with the exp-free A-gen: p = mask ? max(E1*E2[j], F1*F2[j]) : 0.
template <int KTC>
__global__ __launch_bounds__(256, 8)
void pv2_kernel(const unsigned char* __restrict__ adjp,
                const unsigned short* __restrict__ Bpk,
                const float* __restrict__ E1a, const float* __restrict__ F1a,
                const float* __restrict__ E2a, const float* __restrict__ F2a,
                unsigned short* __restrict__ outp, float* __restrict__ lp,
                int out_stride, int N) {
    const int h = blockIdx.y, z = blockIdx.z;
    const int KT = N >> 5;
    const int kt0 = z * KTC;
    const int tid = threadIdx.x;
    const int wave = tid >> 6, lane = tid & 63;
    const int n = lane & 15, q = lane >> 4;
    const int i0w = (blockIdx.x * 4 + wave) * 16;

    __shared__ float e2s[KTC * 32];
    __shared__ float f2s[KTC * 32];
    __shared__ unsigned short ldsB[2][2048];
    __shared__ float lds_l[64];

    const float4* e2src = (const float4*)(E2a + (size_t)h * N + kt0 * 32);
    const float4* f2src = (const float4*)(F2a + (size_t)h * N + kt0 * 32);
    for (int e = tid; e < KTC * 8; e += 256) {
        ((float4*)e2s)[e] = e2src[e];
        ((float4*)f2s)[e] = f2src[e];
    }

    const unsigned short* Bb = Bpk + ((size_t)h * KT + kt0) * 2048;
    uint4 breg = *(const uint4*)(Bb + tid * 8);
    *(uint4*)&ldsB[0][tid * 8] = breg;
    breg = *(const uint4*)(Bb + 2048 + tid * 8);

    const unsigned char* ap = adjp + ((size_t)(i0w >> 4) * KT + kt0) * 64 + lane;
    unsigned int a_c = ap[0];
    unsigned int a_n = ap[64];
    const float E1v = E1a[(size_t)h * N + i0w + n];
    const float F1v = F1a[(size_t)h * N + i0w + n];

    floatx4 acc[4];
    floatx4 accl = {0.f, 0.f, 0.f, 0.f};
#pragma unroll
    for (int g = 0; g < 4; ++g) acc[g] = (floatx4){0.f, 0.f, 0.f, 0.f};

    bf16x8 ones;
    {
        short one = (n == 0) ? (short)0x3F80 : (short)0;
#pragma unroll
        for (int jj = 0; jj < 8; ++jj) ones[jj] = one;
    }

    __syncthreads();

#pragma unroll 2
    for (int k = 0; k < KTC; ++k) {
        if (k + 1 < KTC) *(uint4*)&ldsB[(k + 1) & 1][tid * 8] = breg;
        unsigned int a_2 = 0;
        if (k + 2 < KTC) {
            breg = *(const uint4*)(Bb + (size_t)(k + 2) * 2048 + tid * 8);
            a_2 = ap[(size_t)(k + 2) * 64];
        }

        float4 ea = *(const float4*)&e2s[k * 32 + q * 8];
        float4 eb = *(const float4*)&e2s[k * 32 + q * 8 + 4];
        float4 fa = *(const float4*)&f2s[k * 32 + q * 8];
        float4 fb = *(const float4*)&f2s[k * 32 + q * 8 + 4];
        const float* ev = (const float*)&ea;
        const float* ew = (const float*)&eb;
        const float* fv = (const float*)&fa;
        const float* fw = (const float*)&fb;
        float e[8];
#pragma unroll
        for (int jj = 0; jj < 8; ++jj) {
            float Ej = (jj < 4 ? ev[jj] : ew[jj - 4]);
            float Fj = (jj < 4 ? fv[jj] : fw[jj - 4]);
            float m = fmaxf(E1v * Ej, F1v * Fj);   // exp2(lrelu(s1+s2))
            e[jj] = (a_c & (1u << jj)) ? m : 0.f;
        }
        union { unsigned int u[4]; bf16x8 v; } u;
        u.u[0] = __builtin_amdgcn_perm(__float_as_uint(e[1]), __float_as_uint(e[0]), 0x07060302u);
        u.u[1] = __builtin_amdgcn_perm(__float_as_uint(e[3]), __float_as_uint(e[2]), 0x07060302u);
        u.u[2] = __builtin_amdgcn_perm(__float_as_uint(e[5]), __float_as_uint(e[4]), 0x07060302u);
        u.u[3] = __builtin_amdgcn_perm(__float_as_uint(e[7]), __float_as_uint(e[6]), 0x07060302u);

        bf16x8 bf0 = *(const bf16x8*)&ldsB[k & 1][0 * 512 + lane * 8];
        bf16x8 bf1 = *(const bf16x8*)&ldsB[k & 1][1 * 512 + lane * 8];
        bf16x8 bf2 = *(const bf16x8*)&ldsB[k & 1][2 * 512 + lane * 8];
        bf16x8 bf3 = *(const bf16x8*)&ldsB[k & 1][3 * 512 + lane * 8];

        acc[0] = __builtin_amdgcn_mfma_f32_16x16x32_bf16(u.v, bf0, acc[0], 0, 0, 0);
        acc[1] = __builtin_amdgcn_mfma_f32_16x16x32_bf16(u.v, bf1, acc[1], 0, 0, 0);
        acc[2] = __builtin_amdgcn_mfma_f32_16x16x32_bf16(u.v, bf2, acc[2], 0, 0, 0);
        acc[3] = __builtin_amdgcn_mfma_f32_16x16x32_bf16(u.v, bf3, acc[3], 0, 0, 0);
        accl   = __builtin_amdgcn_mfma_f32_16x16x32_bf16(u.v, ones, accl, 0, 0, 0);

        a_c = a_n;
        a_n = a_2;
        __syncthreads();
    }

    // ---- epilogue: LDS-bounce then coalesced 16B stores ----
    unsigned short* lw = ((unsigned short*)ldsB) + wave * 1024;
#pragma unroll
    for (int r = 0; r < 4; ++r) {
        int row = q * 4 + r;
#pragma unroll
        for (int g = 0; g < 4; ++g)
            lw[row * 64 + g * 16 + n] = f2bf(acc[g][r]);
    }
    if (n == 0) {
#pragma unroll
        for (int r = 0; r < 4; ++r) lds_l[wave * 16 + q * 4 + r] = accl[r];
    }
    __syncthreads();
    unsigned short* obase = outp + ((size_t)z * N + i0w) * out_stride + h * 64;
#pragma unroll
    for (int j = 0; j < 2; ++j) {
        int c = j * 64 + lane;
        int row = c >> 3, ci = c & 7;
        *(uint4*)(obase + (size_t)row * out_stride + ci * 8) =
            *(const uint4*)(lw + row * 64 + ci * 8);
    }
    if (tid < 64) {
        float* lrow = lp + ((size_t)z * gridDim.y + h) * N + blockIdx.x * 64;
        lrow[tid] = lds_l[tid];
    }
}

// whout2: sum bf16 partials, normalize, ELU, GEMM K=256; packed-B + E/F
// score factors for the out layer.
__global__ void whout2_kernel(const unsigned short* __restrict__ hcp,
                              const float* __restrict__ lhp,
                              const float* __restrict__ w_out,
                              const float* __restrict__ a_out,
                              unsigned short* __restrict__ BpkO,
                              float* __restrict__ E1o, float* __restrict__ F1o,
                              float* __restrict__ E2o, float* __restrict__ F2o,
                              int N) {
    int tid = threadIdx.x;
    int i0 = blockIdx.x * 8;
    int KT = N >> 5;
    __shared__ float hs[8][256];
    __shared__ float linv[8][NH];
    if (tid < 8 * NH) {
        int r = tid >> 2, hd = tid & 3;
        float l = 0.f;
#pragma unroll
        for (int p = 0; p < KCH_H; ++p)
            l += lhp[((size_t)p * NH + hd) * N + i0 + r];
        linv[r][hd] = 1.f / fmaxf(l, 1e-30f);
    }
    __syncthreads();
    const size_t ps = (size_t)N * 256;
    for (int e4 = tid; e4 < 8 * 64; e4 += 256) {
        int r = e4 >> 6, k4 = (e4 & 63) * 4;
        size_t off = (size_t)(i0 + r) * 256 + k4;
        float v0 = 0.f, v1 = 0.f, v2 = 0.f, v3 = 0.f;
#pragma unroll
        for (int p = 0; p < KCH_H; ++p) {
            ushort4 u = *(const ushort4*)(hcp + p * ps + off);
            v0 += bf2f(u.x); v1 += bf2f(u.y); v2 += bf2f(u.z); v3 += bf2f(u.w);
        }
        float li = linv[r][k4 >> 6];
        v0 *= li; v1 *= li; v2 *= li; v3 *= li;
        hs[r][k4]     = v0 > 0.f ? v0 : expm1f(v0);
        hs[r][k4 + 1] = v1 > 0.f ? v1 : expm1f(v1);
        hs[r][k4 + 2] = v2 > 0.f ? v2 : expm1f(v2);
        hs[r][k4 + 3] = v3 > 0.f ? v3 : expm1f(v3);
    }
    __syncthreads();
    int f = tid & 63, rl = tid >> 6;
    float a0 = 0.f, a1 = 0.f;
#pragma unroll 4
    for (int k = 0; k < 256; ++k) {
        float wv = w_out[(size_t)k * H + f];
        a0 += hs[rl][k] * wv;
        a1 += hs[rl + 4][k] * wv;
    }
    float w1 = a_out[f], w2 = a_out[H + f];
    float t10 = a0 * w1, t20 = a0 * w2, t11 = a1 * w1, t21 = a1 * w2;
#pragma unroll
    for (int off = 32; off > 0; off >>= 1) {
        t10 += __shfl_xor(t10, off, 64);
        t20 += __shfl_xor(t20, off, 64);
        t11 += __shfl_xor(t11, off, 64);
        t21 += __shfl_xor(t21, off, 64);
    }
    if (f == 0) {
        float s;
        s = t10 * LOG2E;
        E1o[i0 + rl] = __builtin_amdgcn_exp2f(s);
        F1o[i0 + rl] = __builtin_amdgcn_exp2f(0.2f * s);
        s = t20 * LOG2E;
        E2o[i0 + rl] = __builtin_amdgcn_exp2f(s);
        F2o[i0 + rl] = __builtin_amdgcn_exp2f(0.2f * s);
        s = t11 * LOG2E;
        E1o[i0 + rl + 4] = __builtin_amdgcn_exp2f(s);
        F1o[i0 + rl + 4] = __builtin_amdgcn_exp2f(0.2f * s);
        s = t21 * LOG2E;
        E2o[i0 + rl + 4] = __builtin_amdgcn_exp2f(s);
        F2o[i0 + rl + 4] = __builtin_amdgcn_exp2f(0.2f * s);
    }
    __syncthreads();
    float* wsW = &hs[0][0];
    wsW[rl * 64 + f] = a0;
    wsW[(rl + 4) * 64 + f] = a1;
    __syncthreads();
    if (tid < 64) {
        int kt = i0 >> 5, qq = (i0 >> 3) & 3;
        int g = tid >> 4, nn = tid & 15;
        union { unsigned short s[8]; uint4 v; } t;
#pragma unroll
        for (int r = 0; r < 8; ++r) t.s[r] = f2bf(wsW[r * 64 + g * 16 + nn]);
        unsigned short* d = BpkO +
            (((size_t)kt * 4 + g) * 64 + qq * 16 + nn) * 8;
        *(uint4*)d = t.v;
    }
}

// final2: sum bf16 partials, normalize, ELU, + x_res, GEMM, ELU.
__global__ void final2_kernel(const unsigned short* __restrict__ o2p,
                              const float* __restrict__ lop,
                              const float* __restrict__ x_res,
                              const float* __restrict__ outlin_w,
                              const float* __restrict__ outlin_b,
                              float* __restrict__ out, int N) {
    int tid = threadIdx.x;
    int f = tid & 63, rl = tid >> 6;
    int i0 = blockIdx.x * 8;
    __shared__ float hs[8][H];
    __shared__ float linv[8];
    if (tid < 8) {
        float l = 0.f;
#pragma unroll
        for (int p = 0; p < KCH_O; ++p) l += lop[(size_t)p * N + i0 + tid];
        linv[tid] = 1.f / fmaxf(l, 1e-30f);
    }
    __syncthreads();
    const size_t ps = (size_t)N * 64;
    if (tid < 8 * 16) {
        int r = tid >> 4, f4 = (tid & 15) * 4;
        size_t off = (size_t)(i0 + r) * 64 + f4;
        float v0 = 0.f, v1 = 0.f, v2 = 0.f, v3 = 0.f;
#pragma unroll
        for (int p = 0; p < KCH_O; ++p) {
            ushort4 u = *(const ushort4*)(o2p + p * ps + off);
            v0 += bf2f(u.x); v1 += bf2f(u.y); v2 += bf2f(u.z); v3 += bf2f(u.w);
        }
        float li = linv[r];
        v0 *= li; v1 *= li; v2 *= li; v3 *= li;
        v0 = v0 > 0.f ? v0 : expm1f(v0);
        v1 = v1 > 0.f ? v1 : expm1f(v1);
        v2 = v2 > 0.f ? v2 : expm1f(v2);
        v3 = v3 > 0.f ? v3 : expm1f(v3);
        const float* xr = x_res + off;
        hs[r][f4]     = v0 + xr[0];
        hs[r][f4 + 1] = v1 + xr[1];
        hs[r][f4 + 2] = v2 + xr[2];
        hs[r][f4 + 3] = v3 + xr[3];
    }
    __syncthreads();
    float b = outlin_b[f];
    float a0 = b, a1 = b;
#pragma unroll 8
    for (int k = 0; k < H; ++k) {
        float wv = outlin_w[(size_t)f * H + k];
        a0 += hs[rl][k] * wv;
        a1 += hs[rl + 4][k] * wv;
    }
    a0 = a0 > 0.f ? a0 : expm1f(a0);
    a1 = a1 > 0.f ? a1 : expm1f(a1);
    out[(size_t)(i0 + rl) * H + f] = a0;
    out[(size_t)(i0 + rl + 4) * H + f] = a1;
}

extern "C" void kernel_launch(void* const* d_in, const int* in_sizes, int n_in,
                              void* d_out, int out_size, void* d_ws, size_t ws_size,
                              hipStream_t stream) {
    const float* x        = (const float*)d_in[0];
    const int*   adj      = (const int*)d_in[1];
    const float* w_heads  = (const float*)d_in[2];
    const float* a_heads  = (const float*)d_in[3];
    const float* w_out    = (const float*)d_in[4];
    const float* a_out    = (const float*)d_in[5];
    const float* lin_w    = (const float*)d_in[6];
    const float* lin_b    = (const float*)d_in[7];
    const float* outlin_w = (const float*)d_in[8];
    const float* outlin_b = (const float*)d_in[9];
    float* out = (float*)d_out;

    const int N = in_sizes[0] / F_IN;  // 4096
    const int KT = N >> 5;             // 128

    char* p = (char*)d_ws;
    unsigned short* part = (unsigned short*)p;  p += (size_t)KCH_H * N * 256 * 2;  // 32 MB
    float* x_res  = (float*)p;  p += (size_t)N * 64 * 4;
    float* E1h    = (float*)p;  p += (size_t)NH * N * 4;
    float* F1h    = (float*)p;  p += (size_t)NH * N * 4;
    float* E2h    = (float*)p;  p += (size_t)NH * N * 4;
    float* F2h    = (float*)p;  p += (size_t)NH * N * 4;
    float* E1o    = (float*)p;  p += (size_t)N * 4;
    float* F1o    = (float*)p;  p += (size_t)N * 4;
    float* E2o    = (float*)p;  p += (size_t)N * 4;
    float* F2o    = (float*)p;  p += (size_t)N * 4;
    float* lh_part = (float*)p; p += (size_t)KCH_H * NH * N * 4;
    float* lo_part = (float*)p; p += (size_t)KCH_O * N * 4;
    unsigned short* Bpk  = (unsigned short*)p;  p += (size_t)NH * KT * 2048 * 2;
    unsigned short* BpkO = (unsigned short*)p;  p += (size_t)KT * 2048 * 2;
    unsigned char* adjp  = (unsigned char*)p;   p += (size_t)(N / 16) * KT * 64;

    prep_kernel<<<N / 8 + (N / 16) * 8, 256, 0, stream>>>(
        adj, adjp, x, w_heads, a_heads, lin_w, lin_b, Bpk, x_res,
        E1h, F1h, E2h, F2h, N);
    pv2_kernel<8><<<dim3(N / 64, NH, KCH_H), 256, 0, stream>>>(
        adjp, Bpk, E1h, F1h, E2h, F2h, part, lh_part, NH * H, N);
    whout2_kernel<<<N / 8, 256, 0, stream>>>(part, lh_part, w_out, a_out,
                                             BpkO, E1o, F1o, E2o, F2o, N);
    pv2_kernel<4><<<dim3(N / 64, 1, KCH_O), 256, 0, stream>>>(
        adjp, BpkO, E1o, F1o, E2o, F2o, part, lo_part, H, N);
    final2_kernel<<<N / 8, 256, 0, stream>>>(part, lo_part, x_res, outlin_w, outlin_b, out, N);
}

// Round 16
// 189.167 us; speedup vs baseline: 1.0708x; 1.0467x over previous
//
#include <hip/hip_runtime.h>
#include <hip/hip_bf16.h>
#include <stdint.h>

#define F_IN 128
#define H 64
#define NH 4
#define KCH_H 8
#define KCH_O 16
#define LOG2E 1.44269504088896f

typedef __attribute__((ext_vector_type(8))) short bf16x8;
typedef __attribute__((ext_vector_type(4))) float floatx4;

static __device__ __forceinline__ unsigned short f2bf(float v) {
    __hip_bfloat16 b = __float2bfloat16(v);
    return *(unsigned short*)&b;
}
static __device__ __forceinline__ float bf2f(unsigned short u) {
    return __uint_as_float((unsigned int)u << 16);
}

// ---------------------------------------------------------------------------
// prep: blocks [0, N/8) = wh role (Wh->Bpk bf16, x_res, s1h/s2h);
//       blocks [N/8, N/8 + (N/16)*8) = pack role (adj -> fragment bitmask).
__global__ void prep_kernel(const int* __restrict__ adj,
                            unsigned char* __restrict__ adjp,
                            const float* __restrict__ x,
                            const float* __restrict__ w_heads,
                            const float* __restrict__ a_heads,
                            const float* __restrict__ lin_w,
                            const float* __restrict__ lin_b,
                            unsigned short* __restrict__ Bpk,
                            float* __restrict__ x_res,
                            float* __restrict__ s1h,
                            float* __restrict__ s2h, int N) {
    const int bid = blockIdx.x;
    const int tid = threadIdx.x;
    const int KT = N >> 5;
    const int WH_BLOCKS = N / 8;

    if (bid >= WH_BLOCKS) {
        int idx = bid - WH_BLOCKS;
        int it = idx >> 3, rem = idx & 7, half = rem >> 2, zz = rem & 3;
        int i0 = it * 16;
        int n = tid & 15, q = (tid >> 4) & 3, w = tid >> 6;
        const int* row = adj + (size_t)(i0 + n) * N;
        unsigned char* dst = adjp + (size_t)it * KT * 64;
        int ktbase = half * (KT / 2) + zz * 16 + w;
#pragma unroll
        for (int j = 0; j < 4; ++j) {
            int kt = ktbase + 4 * j;
            int c0 = kt * 32 + q * 8;
            int4 a = *(const int4*)(row + c0);
            int4 b = *(const int4*)(row + c0 + 4);
            unsigned byte =
                (unsigned)(a.x > 0) | ((unsigned)(a.y > 0) << 1) |
                ((unsigned)(a.z > 0) << 2) | ((unsigned)(a.w > 0) << 3) |
                ((unsigned)(b.x > 0) << 4) | ((unsigned)(b.y > 0) << 5) |
                ((unsigned)(b.z > 0) << 6) | ((unsigned)(b.w > 0) << 7);
            dst[kt * 64 + q * 16 + n] = (unsigned char)byte;
        }
        return;
    }

    // ---- wh role ----
    int h = tid >> 6, f = tid & 63;
    int i0 = bid * 8;
    __shared__ float xs[8][F_IN];
    __shared__ float lwT[F_IN][65];
    for (int e = tid; e < 8 * F_IN; e += 256)
        xs[e >> 7][e & 127] = x[(size_t)(i0 + (e >> 7)) * F_IN + (e & 127)];
    for (int e = tid; e < 64 * F_IN; e += 256) {
        int ff = e >> 7, k = e & 127;
        lwT[k][ff] = lin_w[e];
    }
    __syncthreads();
    float acc[8];
#pragma unroll
    for (int r = 0; r < 8; ++r) acc[r] = 0.f;
    float xr0 = 0.f, xr1 = 0.f;
    const float* w = w_heads + (size_t)h * F_IN * H + f;
#pragma unroll 4
    for (int k = 0; k < F_IN; ++k) {
        float wv = w[(size_t)k * H];
#pragma unroll
        for (int r = 0; r < 8; ++r) acc[r] += xs[r][k] * wv;
        float wx = lwT[k][f];
        xr0 += xs[h][k] * wx;
        xr1 += xs[h + 4][k] * wx;
    }
    {
        int kt = i0 >> 5, qq = (i0 >> 3) & 3;
        union { unsigned short s[8]; uint4 v; } t;
#pragma unroll
        for (int r = 0; r < 8; ++r) t.s[r] = f2bf(acc[r]);
        unsigned short* d = Bpk +
            (((size_t)(h * KT + kt) * 4 + (f >> 4)) * 64 + qq * 16 + (f & 15)) * 8;
        *(uint4*)d = t.v;
    }
    float b = lin_b[f];
    x_res[(size_t)(i0 + h) * H + f] = xr0 + b;
    x_res[(size_t)(i0 + h + 4) * H + f] = xr1 + b;
    float a1v = a_heads[(size_t)h * 2 * H + f];
    float a2v = a_heads[(size_t)h * 2 * H + H + f];
#pragma unroll
    for (int r = 0; r < 8; ++r) {
        float t1 = acc[r] * a1v;
        float t2 = acc[r] * a2v;
#pragma unroll
        for (int off = 32; off > 0; off >>= 1) {
            t1 += __shfl_xor(t1, off, 64);
            t2 += __shfl_xor(t2, off, 64);
        }
        if (f == 0) {
            s1h[(size_t)h * N + i0 + r] = t1 * LOG2E;
            s2h[(size_t)h * N + i0 + r] = t2 * LOG2E;
        }
    }
}

// ---------------------------------------------------------------------------
// pv2: r13 structure — depth-2 pipelined LDS double-buffer, in-loop exp2,
// LDS-bounced coalesced bf16 partial epilogue.
template <int KTC>
__global__ __launch_bounds__(256, 8)
void pv2_kernel(const unsigned char* __restrict__ adjp,
                const unsigned short* __restrict__ Bpk,
                const float* __restrict__ s1a,
                const float* __restrict__ s2a,
                unsigned short* __restrict__ outp, float* __restrict__ lp,
                int out_stride, int N) {
    const int h = blockIdx.y, z = blockIdx.z;
    const int KT = N >> 5;
    const int kt0 = z * KTC;
    const int tid = threadIdx.x;
    const int wave = tid >> 6, lane = tid & 63;
    const int n = lane & 15, q = lane >> 4;
    const int i0w = (blockIdx.x * 4 + wave) * 16;

    __shared__ float s2s[KTC * 32];
    __shared__ unsigned short ldsB[2][2048];
    __shared__ float lds_l[64];

    const float4* s2src = (const float4*)(s2a + (size_t)h * N + kt0 * 32);
    for (int e = tid; e < KTC * 8; e += 256) ((float4*)s2s)[e] = s2src[e];

    const unsigned short* Bb = Bpk + ((size_t)h * KT + kt0) * 2048;
    uint4 breg = *(const uint4*)(Bb + tid * 8);
    *(uint4*)&ldsB[0][tid * 8] = breg;
    breg = *(const uint4*)(Bb + 2048 + tid * 8);

    const unsigned char* ap = adjp + ((size_t)(i0w >> 4) * KT + kt0) * 64 + lane;
    unsigned int a_c = ap[0];
    unsigned int a_n = ap[64];
    const float s1v = s1a[(size_t)h * N + i0w + n];

    floatx4 acc[4];
    floatx4 accl = {0.f, 0.f, 0.f, 0.f};
#pragma unroll
    for (int g = 0; g < 4; ++g) acc[g] = (floatx4){0.f, 0.f, 0.f, 0.f};

    bf16x8 ones;
    {
        short one = (n == 0) ? (short)0x3F80 : (short)0;
#pragma unroll
        for (int jj = 0; jj < 8; ++jj) ones[jj] = one;
    }

    __syncthreads();

#pragma unroll 2
    for (int k = 0; k < KTC; ++k) {
        if (k + 1 < KTC) *(uint4*)&ldsB[(k + 1) & 1][tid * 8] = breg;
        unsigned int a_2 = 0;
        if (k + 2 < KTC) {
            breg = *(const uint4*)(Bb + (size_t)(k + 2) * 2048 + tid * 8);
            a_2 = ap[(size_t)(k + 2) * 64];
        }

        float4 sa = *(const float4*)&s2s[k * 32 + q * 8];
        float4 sb = *(const float4*)&s2s[k * 32 + q * 8 + 4];
        const float* sv = (const float*)&sa;
        const float* sw = (const float*)&sb;
        float e[8];
#pragma unroll
        for (int jj = 0; jj < 8; ++jj) {
            float sj = (jj < 4 ? sv[jj] : sw[jj - 4]);
            float tt = s1v + sj;
            float lr = fmaxf(tt, 0.2f * tt);
            lr = (a_c & (1u << jj)) ? lr : -150.f;
            e[jj] = __builtin_amdgcn_exp2f(lr);
        }
        union { unsigned int u[4]; bf16x8 v; } u;
        u.u[0] = __builtin_amdgcn_perm(__float_as_uint(e[1]), __float_as_uint(e[0]), 0x07060302u);
        u.u[1] = __builtin_amdgcn_perm(__float_as_uint(e[3]), __float_as_uint(e[2]), 0x07060302u);
        u.u[2] = __builtin_amdgcn_perm(__float_as_uint(e[5]), __float_as_uint(e[4]), 0x07060302u);
        u.u[3] = __builtin_amdgcn_perm(__float_as_uint(e[7]), __float_as_uint(e[6]), 0x07060302u);

        bf16x8 bf0 = *(const bf16x8*)&ldsB[k & 1][0 * 512 + lane * 8];
        bf16x8 bf1 = *(const bf16x8*)&ldsB[k & 1][1 * 512 + lane * 8];
        bf16x8 bf2 = *(const bf16x8*)&ldsB[k & 1][2 * 512 + lane * 8];
        bf16x8 bf3 = *(const bf16x8*)&ldsB[k & 1][3 * 512 + lane * 8];

        acc[0] = __builtin_amdgcn_mfma_f32_16x16x32_bf16(u.v, bf0, acc[0], 0, 0, 0);
        acc[1] = __builtin_amdgcn_mfma_f32_16x16x32_bf16(u.v, bf1, acc[1], 0, 0, 0);
        acc[2] = __builtin_amdgcn_mfma_f32_16x16x32_bf16(u.v, bf2, acc[2], 0, 0, 0);
        acc[3] = __builtin_amdgcn_mfma_f32_16x16x32_bf16(u.v, bf3, acc[3], 0, 0, 0);
        accl   = __builtin_amdgcn_mfma_f32_16x16x32_bf16(u.v, ones, accl, 0, 0, 0);

        a_c = a_n;
        a_n = a_2;
        __syncthreads();
    }

    // ---- epilogue: LDS-bounce then coalesced 16B stores ----
    unsigned short* lw = ((unsigned short*)ldsB) + wave * 1024;
#pragma unroll
    for (int r = 0; r < 4; ++r) {
        int row = q * 4 + r;
#pragma unroll
        for (int g = 0; g < 4; ++g)
            lw[row * 64 + g * 16 + n] = f2bf(acc[g][r]);
    }
    if (n == 0) {
#pragma unroll
        for (int r = 0; r < 4; ++r) lds_l[wave * 16 + q * 4 + r] = accl[r];
    }
    __syncthreads();
    unsigned short* obase = outp + ((size_t)z * N + i0w) * out_stride + h * 64;
#pragma unroll
    for (int j = 0; j < 2; ++j) {
        int c = j * 64 + lane;
        int row = c >> 3, ci = c & 7;
        *(uint4*)(obase + (size_t)row * out_stride + ci * 8) =
            *(const uint4*)(lw + row * 64 + ci * 8);
    }
    if (tid < 64) {
        float* lrow = lp + ((size_t)z * gridDim.y + h) * N + blockIdx.x * 64;
        lrow[tid] = lds_l[tid];
    }
}

// whout2: sum bf16 partials (vectorized), normalize, ELU, GEMM K=256;
// packed-B + folded scores.
__global__ void whout2_kernel(const unsigned short* __restrict__ hcp,
                              const float* __restrict__ lhp,
                              const float* __restrict__ w_out,
                              const float* __restrict__ a_out,
                              unsigned short* __restrict__ BpkO,
                              float* __restrict__ s1o,
                              float* __restrict__ s2o, int N) {
    int tid = threadIdx.x;
    int i0 = blockIdx.x * 8;
    int KT = N >> 5;
    __shared__ float hs[8][256];
    __shared__ float linv[8][NH];
    if (tid < 8 * NH) {
        int r = tid >> 2, hd = tid & 3;
        float l = 0.f;
#pragma unroll
        for (int p = 0; p < KCH_H; ++p)
            l += lhp[((size_t)p * NH + hd) * N + i0 + r];
        linv[r][hd] = 1.f / fmaxf(l, 1e-30f);
    }
    __syncthreads();
    const size_t ps = (size_t)N * 256;
    for (int e4 = tid; e4 < 8 * 64; e4 += 256) {
        int r = e4 >> 6, k4 = (e4 & 63) * 4;
        size_t off = (size_t)(i0 + r) * 256 + k4;
        float v0 = 0.f, v1 = 0.f, v2 = 0.f, v3 = 0.f;
#pragma unroll
        for (int p = 0; p < KCH_H; ++p) {
            ushort4 u = *(const ushort4*)(hcp + p * ps + off);
            v0 += bf2f(u.x); v1 += bf2f(u.y); v2 += bf2f(u.z); v3 += bf2f(u.w);
        }
        float li = linv[r][k4 >> 6];
        v0 *= li; v1 *= li; v2 *= li; v3 *= li;
        hs[r][k4]     = v0 > 0.f ? v0 : expm1f(v0);
        hs[r][k4 + 1] = v1 > 0.f ? v1 : expm1f(v1);
        hs[r][k4 + 2] = v2 > 0.f ? v2 : expm1f(v2);
        hs[r][k4 + 3] = v3 > 0.f ? v3 : expm1f(v3);
    }
    __syncthreads();
    int f = tid & 63, rl = tid >> 6;
    float a0 = 0.f, a1 = 0.f;
#pragma unroll 4
    for (int k = 0; k < 256; ++k) {
        float wv = w_out[(size_t)k * H + f];
        a0 += hs[rl][k] * wv;
        a1 += hs[rl + 4][k] * wv;
    }
    float w1 = a_out[f], w2 = a_out[H + f];
    float t10 = a0 * w1, t20 = a0 * w2, t11 = a1 * w1, t21 = a1 * w2;
#pragma unroll
    for (int off = 32; off > 0; off >>= 1) {
        t10 += __shfl_xor(t10, off, 64);
        t20 += __shfl_xor(t20, off, 64);
        t11 += __shfl_xor(t11, off, 64);
        t21 += __shfl_xor(t21, off, 64);
    }
    if (f == 0) {
        s1o[i0 + rl] = t10 * LOG2E;
        s2o[i0 + rl] = t20 * LOG2E;
        s1o[i0 + rl + 4] = t11 * LOG2E;
        s2o[i0 + rl + 4] = t21 * LOG2E;
    }
    __syncthreads();
    float* wsW = &hs[0][0];
    wsW[rl * 64 + f] = a0;
    wsW[(rl + 4) * 64 + f] = a1;
    __syncthreads();
    if (tid < 64) {
        int kt = i0 >> 5, qq = (i0 >> 3) & 3;
        int g = tid >> 4, nn = tid & 15;
        union { unsigned short s[8]; uint4 v; } t;
#pragma unroll
        for (int r = 0; r < 8; ++r) t.s[r] = f2bf(wsW[r * 64 + g * 16 + nn]);
        unsigned short* d = BpkO +
            (((size_t)kt * 4 + g) * 64 + qq * 16 + nn) * 8;
        *(uint4*)d = t.v;
    }
}

// final2: sum bf16 partials (vectorized), normalize, ELU, + x_res, GEMM, ELU.
__global__ void final2_kernel(const unsigned short* __restrict__ o2p,
                              const float* __restrict__ lop,
                              const float* __restrict__ x_res,
                              const float* __restrict__ outlin_w,
                              const float* __restrict__ outlin_b,
                              float* __restrict__ out, int N) {
    int tid = threadIdx.x;
    int f = tid & 63, rl = tid >> 6;
    int i0 = blockIdx.x * 8;
    __shared__ float hs[8][H];
    __shared__ float linv[8];
    if (tid < 8) {
        float l = 0.f;
#pragma unroll
        for (int p = 0; p < KCH_O; ++p) l += lop[(size_t)p * N + i0 + tid];
        linv[tid] = 1.f / fmaxf(l, 1e-30f);
    }
    __syncthreads();
    const size_t ps = (size_t)N * 64;
    if (tid < 8 * 16) {
        int r = tid >> 4, f4 = (tid & 15) * 4;
        size_t off = (size_t)(i0 + r) * 64 + f4;
        float v0 = 0.f, v1 = 0.f, v2 = 0.f, v3 = 0.f;
#pragma unroll
        for (int p = 0; p < KCH_O; ++p) {
            ushort4 u = *(const ushort4*)(o2p + p * ps + off);
            v0 += bf2f(u.x); v1 += bf2f(u.y); v2 += bf2f(u.z); v3 += bf2f(u.w);
        }
        float li = linv[r];
        v0 *= li; v1 *= li; v2 *= li; v3 *= li;
        v0 = v0 > 0.f ? v0 : expm1f(v0);
        v1 = v1 > 0.f ? v1 : expm1f(v1);
        v2 = v2 > 0.f ? v2 : expm1f(v2);
        v3 = v3 > 0.f ? v3 : expm1f(v3);
        const float* xr = x_res + off;
        hs[r][f4]     = v0 + xr[0];
        hs[r][f4 + 1] = v1 + xr[1];
        hs[r][f4 + 2] = v2 + xr[2];
        hs[r][f4 + 3] = v3 + xr[3];
    }
    __syncthreads();
    float b = outlin_b[f];
    float a0 = b, a1 = b;
#pragma unroll 8
    for (int k = 0; k < H; ++k) {
        float wv = outlin_w[(size_t)f * H + k];
        a0 += hs[rl][k] * wv;
        a1 += hs[rl + 4][k] * wv;
    }
    a0 = a0 > 0.f ? a0 : expm1f(a0);
    a1 = a1 > 0.f ? a1 : expm1f(a1);
    out[(size_t)(i0 + rl) * H + f] = a0;
    out[(size_t)(i0 + rl + 4) * H + f] = a1;
}

extern "C" void kernel_launch(void* const* d_in, const int* in_sizes, int n_in,
                              void* d_out, int out_size, void* d_ws, size_t ws_size,
                              hipStream_t stream) {
    const float* x        = (const float*)d_in[0];
    const int*   adj      = (const int*)d_in[1];
    const float* w_heads  = (const float*)d_in[2];
    const float* a_heads  = (const float*)d_in[3];
    const float* w_out    = (const float*)d_in[4];
    const float* a_out    = (const float*)d_in[5];
    const float* lin_w    = (const float*)d_in[6];
    const float* lin_b    = (const float*)d_in[7];
    const float* outlin_w = (const float*)d_in[8];
    const float* outlin_b = (const float*)d_in[9];
    float* out = (float*)d_out;

    const int N = in_sizes[0] / F_IN;  // 4096
    const int KT = N >> 5;             // 128

    char* p = (char*)d_ws;
    unsigned short* part = (unsigned short*)p;  p += (size_t)KCH_H * N * 256 * 2;  // 16 MB
    float* x_res  = (float*)p;  p += (size_t)N * 64 * 4;
    float* s1h    = (float*)p;  p += (size_t)NH * N * 4;
    float* s2h    = (float*)p;  p += (size_t)NH * N * 4;
    float* s1o    = (float*)p;  p += (size_t)N * 4;
    float* s2o    = (float*)p;  p += (size_t)N * 4;
    float* lh_part = (float*)p; p += (size_t)KCH_H * NH * N * 4;
    float* lo_part = (float*)p; p += (size_t)KCH_O * N * 4;
    unsigned short* Bpk  = (unsigned short*)p;  p += (size_t)NH * KT * 2048 * 2;
    unsigned short* BpkO = (unsigned short*)p;  p += (size_t)KT * 2048 * 2;
    unsigned char* adjp  = (unsigned char*)p;   p += (size_t)(N / 16) * KT * 64;

    prep_kernel<<<N / 8 + (N / 16) * 8, 256, 0, stream>>>(
        adj, adjp, x, w_heads, a_heads, lin_w, lin_b, Bpk, x_res, s1h, s2h, N);
    pv2_kernel<16><<<dim3(N / 64, NH, KCH_H), 256, 0, stream>>>(
        adjp, Bpk, s1h, s2h, part, lh_part, NH * H, N);
    whout2_kernel<<<N / 8, 256, 0, stream>>>(part, lh_part, w_out, a_out,
                                             BpkO, s1o, s2o, N);
    pv2_kernel<8><<<dim3(N / 64, 1, KCH_O), 256, 0, stream>>>(
        adjp, BpkO, s1o, s2o, part, lo_part, H, N);
    final2_kernel<<<N / 8, 256, 0, stream>>>(part, lo_part, x_res, outlin_w, outlin_b, out, N);
}